// Round 1
// baseline (256164.233 us; speedup 1.0000x reference)
//
#include <hip/hip_runtime.h>
#include <hip/hip_bf16.h>
#include <stdint.h>

#define LSEQ 4096

// ---------- helpers ----------
__device__ __forceinline__ float bflo(unsigned int u){ return __uint_as_float(u << 16); }
__device__ __forceinline__ float bfhi(unsigned int u){ return __uint_as_float(u & 0xFFFF0000u); }

__device__ __forceinline__ float wred(float v){
#pragma unroll
  for (int m = 1; m < 64; m <<= 1) v += __shfl_xor(v, m, 64);
  return v;
}

// load 4 consecutive elements (bf16 or f32 source) as float4
__device__ __forceinline__ float4 load4g(const void* base, size_t off, int isb){
  if (isb){
    uint2 u = *(const uint2*)((const unsigned short*)base + off);
    return make_float4(bflo(u.x), bfhi(u.x), bflo(u.y), bfhi(u.y));
  }
  return *(const float4*)((const float*)base + off);
}
__device__ __forceinline__ float load1g(const void* base, int i, int isb){
  if (isb) return __uint_as_float(((unsigned int)((const unsigned short*)base)[i]) << 16);
  return ((const float*)base)[i];
}

// ---------- dtype detector: are float inputs bf16 or f32? ----------
// If E is f32, the low 16 bits of each 32-bit word are mantissa noise -> "wild"
// exponents when interpreted as bf16. If E is bf16, the low half is a real
// N(0,0.5) value -> tame exponent.
__global__ void detect_dtype(const unsigned int* __restrict__ w, int* __restrict__ dflag){
  int tid = threadIdx.x;
  int wild = 0;
  for (int i = tid; i < 4096; i += 256){
    unsigned int lo = w[i] & 0xFFFFu;
    int e = (lo >> 7) & 0xFF;
    if (e < 0x60 || e > 0x9A) wild++;
  }
  __shared__ int cnt;
  if (tid == 0) cnt = 0;
  __syncthreads();
  atomicAdd(&cnt, wild);
  __syncthreads();
  if (tid == 0) *dflag = (cnt * 2 < 4096) ? 1 : 0;  // few wild -> bf16
}

// ---------- per-token embedding max-norm scale ----------
__global__ void embed_scale(const int* __restrict__ tok, const void* __restrict__ E,
                            const int* __restrict__ dflag, float* __restrict__ scale){
  int isb = *dflag;
  int t = blockIdx.x * 4 + (threadIdx.x >> 6);
  int lane = threadIdx.x & 63;
  if (t >= LSEQ) return;
  int token = tok[t];
  float ss = 0.f;
#pragma unroll
  for (int j = 0; j < 2; ++j){
    float4 v = load4g(E, (size_t)token * 512 + 4 * lane + 256 * j, isb);
    ss += v.x * v.x + v.y * v.y + v.z * v.z + v.w * v.w;
  }
  ss = wred(ss);
  if (lane == 0){
    float nrm = sqrtf(ss);
    scale[t] = fminf(1.0f, 1.0f / fmaxf(nrm, 1e-7f));
  }
}

// ---------- persistent pipelined 2-layer GRU ----------
// grid = 256 WGs x 512 threads (8 waves). WG b, wave v:
//   waves 0-3: layer0 h-index  b*4+v   (recurrent W_hh0 dot h0, input W_ih0 dot E-row)
//   waves 4-7: layer1 h-index  b*4+v-4 (input W_ih1 dot h0,     recurrent W_hh1 dot h1)
// Superstep s: compute h0[s] and h1[s-1]; one flag-barrier per superstep.
__global__ __launch_bounds__(512, 2) void gru_persistent(
    const int* __restrict__ tok, const void* __restrict__ E,
    const void* __restrict__ Wih0, const void* __restrict__ Whh0,
    const void* __restrict__ bih0, const void* __restrict__ bhh0,
    const void* __restrict__ Wih1, const void* __restrict__ Whh1,
    const void* __restrict__ bih1, const void* __restrict__ bhh1,
    float* __restrict__ wsf, void* __restrict__ outv)
{
  __shared__ float4 h0l[256];
  __shared__ float4 h1l[256];
  int* flags = (int*)wsf;                 // [0..255]
  const int isb = ((const int*)wsf)[256]; // dtype flag
  float* h0buf = wsf + 512;               // 2 x 1024 f32 (double buffer)
  float* h1buf = wsf + 2560;              // 2 x 1024 f32
  const float* scale = wsf + 4608;        // 4096 f32

  const int tid = threadIdx.x, bid = blockIdx.x;
  const int wave = tid >> 6, lane = tid & 63;
  const bool isL0 = wave < 4;
  const int hidx = bid * 4 + (wave & 3);

  // ---- load weight fragments into registers (one time) ----
  // k-mapping: lane holds elements k = 4*lane + 256*j + {0..3}
  float4 WA[3][4], WB[3][4];
  float bIr[3], bRr[3];
#pragma unroll
  for (int g = 0; g < 3; ++g){
    size_t row = (size_t)(g * 1024 + hidx);
    if (isL0){
#pragma unroll
      for (int j = 0; j < 4; ++j) WA[g][j] = load4g(Whh0, row * 1024 + 4 * lane + 256 * j, isb);
#pragma unroll
      for (int j = 0; j < 2; ++j) WB[g][j] = load4g(Wih0, row * 512 + 4 * lane + 256 * j, isb);
      WB[g][2] = make_float4(0, 0, 0, 0); WB[g][3] = make_float4(0, 0, 0, 0);
      bIr[g] = load1g(bih0, g * 1024 + hidx, isb);
      bRr[g] = load1g(bhh0, g * 1024 + hidx, isb);
    } else {
#pragma unroll
      for (int j = 0; j < 4; ++j) WA[g][j] = load4g(Wih1, row * 1024 + 4 * lane + 256 * j, isb);
#pragma unroll
      for (int j = 0; j < 4; ++j) WB[g][j] = load4g(Whh1, row * 1024 + 4 * lane + 256 * j, isb);
      bIr[g] = load1g(bih1, g * 1024 + hidx, isb);
      bRr[g] = load1g(bhh1, g * 1024 + hidx, isb);
    }
  }

  for (int s = 0; s <= LSEQ; ++s){
    const int rsl = (s + 1) & 1, wsl = s & 1;
    // stage h vectors (written by all WGs last superstep) into LDS
    if (tid < 256) h0l[tid]       = ((const float4*)(h0buf + rsl * 1024))[tid];
    else           h1l[tid - 256] = ((const float4*)(h1buf + rsl * 1024))[tid - 256];
    __syncthreads();

    const bool active = isL0 ? (s < LSEQ) : (s >= 1);
    if (active){
      const int t = isL0 ? s : (s - 1);
      float4 xr[4];
      float sc = 1.0f;
      if (isL0){
        int token = tok[t];
        sc = scale[t];
        xr[0] = load4g(E, (size_t)token * 512 + 4 * lane, isb);
        xr[1] = load4g(E, (size_t)token * 512 + 4 * lane + 256, isb);
        xr[2] = make_float4(0, 0, 0, 0); xr[3] = make_float4(0, 0, 0, 0);
      } else {
#pragma unroll
        for (int j = 0; j < 4; ++j) xr[j] = h1l[lane + 64 * j];
      }
      float4 h0r[4];
#pragma unroll
      for (int j = 0; j < 4; ++j) h0r[j] = h0l[lane + 64 * j];

      float a1r = 0, a1z = 0, a1n = 0, a2r = 0, a2z = 0, a2n = 0;
#pragma unroll
      for (int j = 0; j < 4; ++j){
        float4 h = h0r[j], x = xr[j], w;
        w = WA[0][j]; a1r = fmaf(w.w, h.w, fmaf(w.z, h.z, fmaf(w.y, h.y, fmaf(w.x, h.x, a1r))));
        w = WA[1][j]; a1z = fmaf(w.w, h.w, fmaf(w.z, h.z, fmaf(w.y, h.y, fmaf(w.x, h.x, a1z))));
        w = WA[2][j]; a1n = fmaf(w.w, h.w, fmaf(w.z, h.z, fmaf(w.y, h.y, fmaf(w.x, h.x, a1n))));
        w = WB[0][j]; a2r = fmaf(w.w, x.w, fmaf(w.z, x.z, fmaf(w.y, x.y, fmaf(w.x, x.x, a2r))));
        w = WB[1][j]; a2z = fmaf(w.w, x.w, fmaf(w.z, x.z, fmaf(w.y, x.y, fmaf(w.x, x.x, a2z))));
        w = WB[2][j]; a2n = fmaf(w.w, x.w, fmaf(w.z, x.z, fmaf(w.y, x.y, fmaf(w.x, x.x, a2n))));
      }
      a1r = wred(a1r); a1z = wred(a1z); a1n = wred(a1n);
      a2r = wred(a2r); a2z = wred(a2z); a2n = wred(a2n);

      float ipr, ipz, ipn, rpr, rpz, rpn;
      if (isL0){ ipr = sc * a2r + bIr[0]; ipz = sc * a2z + bIr[1]; ipn = sc * a2n + bIr[2];
                 rpr = a1r + bRr[0];      rpz = a1z + bRr[1];      rpn = a1n + bRr[2]; }
      else     { ipr = a1r + bIr[0];      ipz = a1z + bIr[1];      ipn = a1n + bIr[2];
                 rpr = a2r + bRr[0];      rpz = a2z + bRr[1];      rpn = a2n + bRr[2]; }

      float r = 1.0f / (1.0f + expf(-(ipr + rpr)));
      float z = 1.0f / (1.0f + expf(-(ipz + rpz)));
      float n = tanhf(ipn + r * rpn);
      float hprev = isL0 ? ((const float*)h0l)[hidx] : ((const float*)h1l)[hidx];
      float hnew = (1.0f - z) * n + z * hprev;

      if (lane == 0){
        float* dst = (isL0 ? h0buf : h1buf) + wsl * 1024;
        dst[hidx] = hnew;
        if (isb){
          __hip_bfloat16* ob = (__hip_bfloat16*)outv;
          if (isL0 && s == LSEQ - 1) ob[1024 + hidx] = __float2bfloat16(hnew);       // hidden[0]
          if (!isL0 && s == LSEQ)  { ob[hidx] = __float2bfloat16(hnew);              // out
                                     ob[2048 + hidx] = __float2bfloat16(hnew); }     // hidden[1]
        } else {
          float* of = (float*)outv;
          if (isL0 && s == LSEQ - 1) of[1024 + hidx] = hnew;
          if (!isL0 && s == LSEQ)  { of[hidx] = hnew; of[2048 + hidx] = hnew; }
        }
      }
    }

    // ---- distributed grid barrier (release -> flag -> poll -> acquire) ----
    if (s < LSEQ){
      __threadfence();     // release: drain h stores to device scope (L2 wb)
      __syncthreads();
      if (tid == 0)
        __hip_atomic_store(&flags[bid], s + 1, __ATOMIC_RELAXED, __HIP_MEMORY_SCOPE_AGENT);
      if (tid < 256){
        while (__hip_atomic_load(&flags[tid], __ATOMIC_RELAXED, __HIP_MEMORY_SCOPE_AGENT) <= s)
          __builtin_amdgcn_s_sleep(1);
      }
      __syncthreads();
      __threadfence();     // acquire: invalidate stale L1/L2 before reading new h
    }
  }
}

extern "C" void kernel_launch(void* const* d_in, const int* in_sizes, int n_in,
                              void* d_out, int out_size, void* d_ws, size_t ws_size,
                              hipStream_t stream) {
  const int*  tokens = (const int*)d_in[0];
  const void* E    = d_in[1];
  const void* Wih0 = d_in[2];
  const void* Whh0 = d_in[3];
  const void* bih0 = d_in[4];
  const void* bhh0 = d_in[5];
  const void* Wih1 = d_in[6];
  const void* Whh1 = d_in[7];
  const void* bih1 = d_in[8];
  const void* bhh1 = d_in[9];
  float* wsf = (float*)d_ws;

  // zero: barrier flags (1KB) + dtype flag + pad (1KB) + h0 (8KB) + h1 (8KB)
  hipMemsetAsync(d_ws, 0, 18432, stream);
  hipLaunchKernelGGL(detect_dtype, dim3(1), dim3(256), 0, stream,
                     (const unsigned int*)E, ((int*)d_ws) + 256);
  hipLaunchKernelGGL(embed_scale, dim3(1024), dim3(256), 0, stream,
                     tokens, E, ((const int*)d_ws) + 256, wsf + 4608);

  void* args[] = { (void*)&tokens, (void*)&E, (void*)&Wih0, (void*)&Whh0,
                   (void*)&bih0, (void*)&bhh0, (void*)&Wih1, (void*)&Whh1,
                   (void*)&bih1, (void*)&bhh1, (void*)&wsf, (void*)&d_out };
  hipLaunchCooperativeKernel((void*)gru_persistent, dim3(256), dim3(512),
                             args, 0, stream);
}

// Round 2
// 28253.336 us; speedup vs baseline: 9.0667x; 9.0667x over previous
//
#include <hip/hip_runtime.h>
#include <hip/hip_bf16.h>
#include <stdint.h>

#define LSEQ 4096

// ---------- helpers ----------
__device__ __forceinline__ float bflo(unsigned int u){ return __uint_as_float(u << 16); }
__device__ __forceinline__ float bfhi(unsigned int u){ return __uint_as_float(u & 0xFFFF0000u); }

__device__ __forceinline__ float wred(float v){
#pragma unroll
  for (int m = 1; m < 64; m <<= 1) v += __shfl_xor(v, m, 64);
  return v;
}

// agent-scope (sc0 sc1, L1+L2-bypassing) load/store — the ONLY way WGs talk.
__device__ __forceinline__ float gload(const float* p){
  return __hip_atomic_load(p, __ATOMIC_RELAXED, __HIP_MEMORY_SCOPE_AGENT);
}
__device__ __forceinline__ void gstore(float* p, float v){
  __hip_atomic_store(p, v, __ATOMIC_RELAXED, __HIP_MEMORY_SCOPE_AGENT);
}

// load 4 consecutive elements (bf16 or f32 source) as float4
__device__ __forceinline__ float4 load4g(const void* base, size_t off, int isb){
  if (isb){
    uint2 u = *(const uint2*)((const unsigned short*)base + off);
    return make_float4(bflo(u.x), bfhi(u.x), bflo(u.y), bfhi(u.y));
  }
  return *(const float4*)((const float*)base + off);
}
__device__ __forceinline__ float load1g(const void* base, int i, int isb){
  if (isb) return __uint_as_float(((unsigned int)((const unsigned short*)base)[i]) << 16);
  return ((const float*)base)[i];
}

// ---------- dtype detector: are float inputs bf16 or f32? ----------
__global__ void detect_dtype(const unsigned int* __restrict__ w, int* __restrict__ dflag){
  int tid = threadIdx.x;
  int wild = 0;
  for (int i = tid; i < 4096; i += 256){
    unsigned int lo = w[i] & 0xFFFFu;
    int e = (lo >> 7) & 0xFF;
    if (e < 0x60 || e > 0x9A) wild++;
  }
  __shared__ int cnt;
  if (tid == 0) cnt = 0;
  __syncthreads();
  atomicAdd(&cnt, wild);
  __syncthreads();
  if (tid == 0) *dflag = (cnt * 2 < 4096) ? 1 : 0;  // few wild -> bf16
}

// ---------- per-token embedding max-norm scale ----------
__global__ void embed_scale(const int* __restrict__ tok, const void* __restrict__ E,
                            const int* __restrict__ dflag, float* __restrict__ scale){
  int isb = *dflag;
  int t = blockIdx.x * 4 + (threadIdx.x >> 6);
  int lane = threadIdx.x & 63;
  if (t >= LSEQ) return;
  int token = tok[t];
  float ss = 0.f;
#pragma unroll
  for (int j = 0; j < 2; ++j){
    float4 v = load4g(E, (size_t)token * 512 + 4 * lane + 256 * j, isb);
    ss += v.x * v.x + v.y * v.y + v.z * v.z + v.w * v.w;
  }
  ss = wred(ss);
  if (lane == 0){
    float nrm = sqrtf(ss);
    scale[t] = fminf(1.0f, 1.0f / fmaxf(nrm, 1e-7f));
  }
}

// ---------- persistent pipelined 2-layer GRU ----------
// grid = 256 WGs x 512 threads (8 waves). WG b, wave v:
//   waves 0-3: layer0 h-row b*4+v;  waves 4-7: layer1 h-row b*4+v-4.
// Superstep s computes h0[s] and h1[s-1]. Cross-WG traffic is exclusively
// agent-scope (sc1) atomics -> no __threadfence / L2 writeback storms.
__global__ __launch_bounds__(512, 2) void gru_persistent(
    const int* __restrict__ tok, const void* __restrict__ E,
    const void* __restrict__ Wih0, const void* __restrict__ Whh0,
    const void* __restrict__ bih0, const void* __restrict__ bhh0,
    const void* __restrict__ Wih1, const void* __restrict__ Whh1,
    const void* __restrict__ bih1, const void* __restrict__ bhh1,
    float* __restrict__ wsf, void* __restrict__ outv)
{
  __shared__ float hb[2048];              // staged h0 (0..1023) | h1 (1024..2047)
  int* flags = (int*)wsf;                 // [0..255]
  const int isb = ((const int*)wsf)[256]; // dtype flag
  float* h0buf = wsf + 512;               // 2 x 1024 f32 (double buffer)
  float* h1buf = wsf + 2560;              // 2 x 1024 f32
  const float* scale = wsf + 4608;        // 4096 f32

  const int tid = threadIdx.x, bid = blockIdx.x;
  const int wave = tid >> 6, lane = tid & 63;
  const bool isL0 = wave < 4;
  const int hidx = bid * 4 + (wave & 3);

  // ---- load weight fragments into registers (one time) ----
  float4 WA[3][4], WB[3][4];
  float bIr[3], bRr[3];
#pragma unroll
  for (int g = 0; g < 3; ++g){
    size_t row = (size_t)(g * 1024 + hidx);
    if (isL0){
#pragma unroll
      for (int j = 0; j < 4; ++j) WA[g][j] = load4g(Whh0, row * 1024 + 4 * lane + 256 * j, isb);
#pragma unroll
      for (int j = 0; j < 2; ++j) WB[g][j] = load4g(Wih0, row * 512 + 4 * lane + 256 * j, isb);
      WB[g][2] = make_float4(0, 0, 0, 0); WB[g][3] = make_float4(0, 0, 0, 0);
      bIr[g] = load1g(bih0, g * 1024 + hidx, isb);
      bRr[g] = load1g(bhh0, g * 1024 + hidx, isb);
    } else {
#pragma unroll
      for (int j = 0; j < 4; ++j) WA[g][j] = load4g(Wih1, row * 1024 + 4 * lane + 256 * j, isb);
#pragma unroll
      for (int j = 0; j < 4; ++j) WB[g][j] = load4g(Whh1, row * 1024 + 4 * lane + 256 * j, isb);
      bIr[g] = load1g(bih1, g * 1024 + hidx, isb);
      bRr[g] = load1g(bhh1, g * 1024 + hidx, isb);
    }
  }

  for (int s = 0; s <= LSEQ; ++s){
    const int rsl = (s + 1) & 1, wsl = s & 1;
    // stage h0/h1 from LLC into LDS (sc1 loads — always fresh)
#pragma unroll
    for (int k = 0; k < 4; ++k){
      int i = tid + 512 * k;
      const float* src = (i < 1024) ? (h0buf + rsl * 1024 + i)
                                    : (h1buf + rsl * 1024 + (i - 1024));
      hb[i] = gload(src);
    }
    __syncthreads();

    const bool active = isL0 ? (s < LSEQ) : (s >= 1);
    if (active){
      const int t = isL0 ? s : (s - 1);
      float4 xr[4];
      float sc = 1.0f;
      if (isL0){
        int token = tok[t];
        sc = scale[t];
        xr[0] = load4g(E, (size_t)token * 512 + 4 * lane, isb);
        xr[1] = load4g(E, (size_t)token * 512 + 4 * lane + 256, isb);
        xr[2] = make_float4(0, 0, 0, 0); xr[3] = make_float4(0, 0, 0, 0);
      } else {
#pragma unroll
        for (int j = 0; j < 4; ++j) xr[j] = ((const float4*)(hb + 1024))[lane + 64 * j];
      }
      float4 h0r[4];
#pragma unroll
      for (int j = 0; j < 4; ++j) h0r[j] = ((const float4*)hb)[lane + 64 * j];

      float a1r = 0, a1z = 0, a1n = 0, a2r = 0, a2z = 0, a2n = 0;
#pragma unroll
      for (int j = 0; j < 4; ++j){
        float4 h = h0r[j], x = xr[j], w;
        w = WA[0][j]; a1r = fmaf(w.w, h.w, fmaf(w.z, h.z, fmaf(w.y, h.y, fmaf(w.x, h.x, a1r))));
        w = WA[1][j]; a1z = fmaf(w.w, h.w, fmaf(w.z, h.z, fmaf(w.y, h.y, fmaf(w.x, h.x, a1z))));
        w = WA[2][j]; a1n = fmaf(w.w, h.w, fmaf(w.z, h.z, fmaf(w.y, h.y, fmaf(w.x, h.x, a1n))));
        w = WB[0][j]; a2r = fmaf(w.w, x.w, fmaf(w.z, x.z, fmaf(w.y, x.y, fmaf(w.x, x.x, a2r))));
        w = WB[1][j]; a2z = fmaf(w.w, x.w, fmaf(w.z, x.z, fmaf(w.y, x.y, fmaf(w.x, x.x, a2z))));
        w = WB[2][j]; a2n = fmaf(w.w, x.w, fmaf(w.z, x.z, fmaf(w.y, x.y, fmaf(w.x, x.x, a2n))));
      }
      a1r = wred(a1r); a1z = wred(a1z); a1n = wred(a1n);
      a2r = wred(a2r); a2z = wred(a2z); a2n = wred(a2n);

      float ipr, ipz, ipn, rpr, rpz, rpn;
      if (isL0){ ipr = sc * a2r + bIr[0]; ipz = sc * a2z + bIr[1]; ipn = sc * a2n + bIr[2];
                 rpr = a1r + bRr[0];      rpz = a1z + bRr[1];      rpn = a1n + bRr[2]; }
      else     { ipr = a1r + bIr[0];      ipz = a1z + bIr[1];      ipn = a1n + bIr[2];
                 rpr = a2r + bRr[0];      rpz = a2z + bRr[1];      rpn = a2n + bRr[2]; }

      float r = 1.0f / (1.0f + expf(-(ipr + rpr)));
      float z = 1.0f / (1.0f + expf(-(ipz + rpz)));
      float n = tanhf(ipn + r * rpn);
      float hprev = isL0 ? hb[hidx] : hb[1024 + hidx];
      float hnew = (1.0f - z) * n + z * hprev;

      if (lane == 0){
        float* dst = (isL0 ? h0buf : h1buf) + wsl * 1024;
        gstore(&dst[hidx], hnew);   // sc1: straight to coherence point
        if (isb){
          __hip_bfloat16* ob = (__hip_bfloat16*)outv;
          if (isL0 && s == LSEQ - 1) ob[1024 + hidx] = __float2bfloat16(hnew);       // hidden[0]
          if (!isL0 && s == LSEQ)  { ob[hidx] = __float2bfloat16(hnew);              // out
                                     ob[2048 + hidx] = __float2bfloat16(hnew); }     // hidden[1]
        } else {
          float* of = (float*)outv;
          if (isL0 && s == LSEQ - 1) of[1024 + hidx] = hnew;
          if (!isL0 && s == LSEQ)  { of[hidx] = hnew; of[2048 + hidx] = hnew; }
        }
      }
    }

    // ---- distributed grid barrier: drain sc1 stores, set flag, poll flags ----
    if (s < LSEQ){
      asm volatile("s_waitcnt vmcnt(0)" ::: "memory");  // h stores at coherence point
      __syncthreads();                                   // all waves drained
      if (tid == 0)
        __hip_atomic_store(&flags[bid], s + 1, __ATOMIC_RELAXED, __HIP_MEMORY_SCOPE_AGENT);
      if (tid < 256){
        while (__hip_atomic_load(&flags[tid], __ATOMIC_RELAXED, __HIP_MEMORY_SCOPE_AGENT) <= s)
          __builtin_amdgcn_s_sleep(1);
      }
      __syncthreads();
    }
  }
}

extern "C" void kernel_launch(void* const* d_in, const int* in_sizes, int n_in,
                              void* d_out, int out_size, void* d_ws, size_t ws_size,
                              hipStream_t stream) {
  const int*  tokens = (const int*)d_in[0];
  const void* E    = d_in[1];
  const void* Wih0 = d_in[2];
  const void* Whh0 = d_in[3];
  const void* bih0 = d_in[4];
  const void* bhh0 = d_in[5];
  const void* Wih1 = d_in[6];
  const void* Whh1 = d_in[7];
  const void* bih1 = d_in[8];
  const void* bhh1 = d_in[9];
  float* wsf = (float*)d_ws;

  // zero: barrier flags (1KB) + dtype flag + pad (1KB) + h0 (8KB) + h1 (8KB)
  hipMemsetAsync(d_ws, 0, 18432, stream);
  hipLaunchKernelGGL(detect_dtype, dim3(1), dim3(256), 0, stream,
                     (const unsigned int*)E, ((int*)d_ws) + 256);
  hipLaunchKernelGGL(embed_scale, dim3(1024), dim3(256), 0, stream,
                     tokens, E, ((const int*)d_ws) + 256, wsf + 4608);

  void* args[] = { (void*)&tokens, (void*)&E, (void*)&Wih0, (void*)&Whh0,
                   (void*)&bih0, (void*)&bhh0, (void*)&Wih1, (void*)&Whh1,
                   (void*)&bih1, (void*)&bhh1, (void*)&wsf, (void*)&d_out };
  hipLaunchCooperativeKernel((void*)gru_persistent, dim3(256), dim3(512),
                             args, 0, stream);
}

// Round 5
// 14804.356 us; speedup vs baseline: 17.3033x; 1.9084x over previous
//
#include <hip/hip_runtime.h>
#include <hip/hip_bf16.h>
#include <stdint.h>

#define LSEQ 4096

typedef float f32x4 __attribute__((ext_vector_type(4)));
typedef int   i32x4 __attribute__((ext_vector_type(4)));

// ---------- helpers ----------
__device__ __forceinline__ float bflo(unsigned int u){ return __uint_as_float(u << 16); }
__device__ __forceinline__ float bfhi(unsigned int u){ return __uint_as_float(u & 0xFFFF0000u); }

__device__ __forceinline__ float wred(float v){
#pragma unroll
  for (int m = 1; m < 64; m <<= 1) v += __shfl_xor(v, m, 64);
  return v;
}

// pin a float4 into VGPRs component-wise (tied aggregate constraints are
// unsupported on gfx950 -> tie each scalar VGPR individually)
__device__ __forceinline__ void keep4(float4 &v){
  asm volatile("" : "+v"(v.x), "+v"(v.y), "+v"(v.z), "+v"(v.w));
}

// raw L1/L2-bypassing (sc0 sc1) vector ops — coherent at LLC, compiler-opaque.
// ext_vector types lower to native VGPR tuples in asm constraints (struct
// float4 does NOT — "indirect register inputs" error).
__device__ __forceinline__ f32x4 ld4_sc(const float* p){
  f32x4 r;
  asm volatile("global_load_dwordx4 %0, %1, off sc0 sc1\n\ts_waitcnt vmcnt(0)"
               : "=v"(r) : "v"(p) : "memory");
  return r;
}
__device__ __forceinline__ i32x4 ld4i_sc(const int* p){
  i32x4 r;
  asm volatile("global_load_dwordx4 %0, %1, off sc0 sc1\n\ts_waitcnt vmcnt(0)"
               : "=v"(r) : "v"(p) : "memory");
  return r;
}
__device__ __forceinline__ void st4_sc(float* p, f32x4 v){
  asm volatile("global_store_dwordx4 %0, %1, off sc0 sc1" :: "v"(p), "v"(v) : "memory");
}

// load 4 consecutive elements (bf16 or f32 source) as float4 (normal cached path)
__device__ __forceinline__ float4 load4g(const void* base, size_t off, int isb){
  if (isb){
    uint2 u = *(const uint2*)((const unsigned short*)base + off);
    return make_float4(bflo(u.x), bfhi(u.x), bflo(u.y), bfhi(u.y));
  }
  return *(const float4*)((const float*)base + off);
}
__device__ __forceinline__ float load1g(const void* base, int i, int isb){
  if (isb) return __uint_as_float(((unsigned int)((const unsigned short*)base)[i]) << 16);
  return ((const float*)base)[i];
}

// ---------- dtype detector ----------
__global__ void detect_dtype(const unsigned int* __restrict__ w, int* __restrict__ dflag){
  int tid = threadIdx.x;
  int wild = 0;
  for (int i = tid; i < 4096; i += 256){
    unsigned int lo = w[i] & 0xFFFFu;
    int e = (lo >> 7) & 0xFF;
    if (e < 0x60 || e > 0x9A) wild++;
  }
  __shared__ int cnt;
  if (tid == 0) cnt = 0;
  __syncthreads();
  atomicAdd(&cnt, wild);
  __syncthreads();
  if (tid == 0) *dflag = (cnt * 2 < 4096) ? 1 : 0;
}

// ---------- per-token embedding max-norm scale ----------
__global__ void embed_scale(const int* __restrict__ tok, const void* __restrict__ E,
                            const int* __restrict__ dflag, float* __restrict__ scale){
  int isb = *dflag;
  int t = blockIdx.x * 4 + (threadIdx.x >> 6);
  int lane = threadIdx.x & 63;
  if (t >= LSEQ) return;
  int token = tok[t];
  float ss = 0.f;
#pragma unroll
  for (int j = 0; j < 2; ++j){
    float4 v = load4g(E, (size_t)token * 512 + 4 * lane + 256 * j, isb);
    ss += v.x * v.x + v.y * v.y + v.z * v.z + v.w * v.w;
  }
  ss = wred(ss);
  if (lane == 0){
    float nrm = sqrtf(ss);
    scale[t] = fminf(1.0f, 1.0f / fmaxf(nrm, 1e-7f));
  }
}

// ---------- persistent pipelined 2-layer GRU ----------
// 256 WGs x 512 thr. Waves 0-3: layer0 rows 4b..4b+3; waves 4-7: layer1 rows.
// Workspace layout (floats): [0..255] flags | [256] dtype | [512..4607] hall[2][2048]
// (h0 at +0, h1 at +1024 per slot) | [4608..8703] scale.
__global__ __launch_bounds__(512, 2) void gru_persistent(
    const int* __restrict__ tok, const void* __restrict__ E,
    const void* __restrict__ Wih0, const void* __restrict__ Whh0,
    const void* __restrict__ bih0, const void* __restrict__ bhh0,
    const void* __restrict__ Wih1, const void* __restrict__ Whh1,
    const void* __restrict__ bih1, const void* __restrict__ bhh1,
    float* __restrict__ wsf, void* __restrict__ outv)
{
  __shared__ float hb[2048];   // staged h0 (0..1023) | h1 (1024..2047)
  __shared__ float out8[8];    // this WG's 8 new h values
  int* flags = (int*)wsf;
  const int isb = ((const int*)wsf)[256];
  float* hall = wsf + 512;     // 2 slots x 2048
  const float* scale = wsf + 4608;

  const int tid = threadIdx.x, bid = blockIdx.x;
  const int wave = tid >> 6, lane = tid & 63;
  const bool isL0 = wave < 4;
  const int hidx = bid * 4 + (wave & 3);

  // ---- one-time weight load into registers, pinned ----
  float4 WA[3][4], WB[3][4];
  float bIr[3], bRr[3];
#pragma unroll
  for (int g = 0; g < 3; ++g){
    size_t row = (size_t)(g * 1024 + hidx);
    if (isL0){
#pragma unroll
      for (int j = 0; j < 4; ++j) WA[g][j] = load4g(Whh0, row * 1024 + 4 * lane + 256 * j, isb);
#pragma unroll
      for (int j = 0; j < 2; ++j) WB[g][j] = load4g(Wih0, row * 512 + 4 * lane + 256 * j, isb);
      WB[g][2] = make_float4(0, 0, 0, 0); WB[g][3] = make_float4(0, 0, 0, 0);
      bIr[g] = load1g(bih0, g * 1024 + hidx, isb);
      bRr[g] = load1g(bhh0, g * 1024 + hidx, isb);
    } else {
#pragma unroll
      for (int j = 0; j < 4; ++j) WA[g][j] = load4g(Wih1, row * 1024 + 4 * lane + 256 * j, isb);
#pragma unroll
      for (int j = 0; j < 4; ++j) WB[g][j] = load4g(Whh1, row * 1024 + 4 * lane + 256 * j, isb);
      bIr[g] = load1g(bih1, g * 1024 + hidx, isb);
      bRr[g] = load1g(bhh1, g * 1024 + hidx, isb);
    }
  }
#pragma unroll
  for (int g = 0; g < 3; ++g)
#pragma unroll
    for (int j = 0; j < 4; ++j){ keep4(WA[g][j]); keep4(WB[g][j]); }

  // ---- prologue prefetch: token 0 ----
  float4 xpre0 = make_float4(0,0,0,0), xpre1 = make_float4(0,0,0,0);
  float sc_next = 1.0f;
  if (isL0){
    int t0 = tok[0];
    sc_next = scale[0];
    xpre0 = load4g(E, (size_t)t0 * 512 + 4 * lane, isb);
    xpre1 = load4g(E, (size_t)t0 * 512 + 4 * lane + 256, isb);
  }

  for (int s = 0; s <= LSEQ; ++s){
    const int rsl = (s + 1) & 1, wsl = s & 1;
    // stage h0|h1 from LLC into LDS: ONE dwordx4 sc1 load per thread
    f32x4 st = ld4_sc(hall + rsl * 2048 + 4 * tid);
    hb[4 * tid + 0] = st.x; hb[4 * tid + 1] = st.y;
    hb[4 * tid + 2] = st.z; hb[4 * tid + 3] = st.w;
    __syncthreads();

    const bool active = isL0 ? (s < LSEQ) : (s >= 1);
    float hprev = isL0 ? hb[hidx] : hb[1024 + hidx];
    float hnew = hprev;
    if (active){
      float4 xr[4];
      float sc = 1.0f;
      if (isL0){
        sc = sc_next;
        xr[0] = xpre0; xr[1] = xpre1;
        xr[2] = make_float4(0,0,0,0); xr[3] = make_float4(0,0,0,0);
      } else {
#pragma unroll
        for (int j = 0; j < 4; ++j) xr[j] = ((const float4*)(hb + 1024))[lane + 64 * j];
      }
      float4 h0r[4];
#pragma unroll
      for (int j = 0; j < 4; ++j) h0r[j] = ((const float4*)hb)[lane + 64 * j];

      float a1r = 0, a1z = 0, a1n = 0, a2r = 0, a2z = 0, a2n = 0;
#pragma unroll
      for (int j = 0; j < 4; ++j){
        float4 h = h0r[j], x = xr[j], w;
        w = WA[0][j]; a1r = fmaf(w.w, h.w, fmaf(w.z, h.z, fmaf(w.y, h.y, fmaf(w.x, h.x, a1r))));
        w = WA[1][j]; a1z = fmaf(w.w, h.w, fmaf(w.z, h.z, fmaf(w.y, h.y, fmaf(w.x, h.x, a1z))));
        w = WA[2][j]; a1n = fmaf(w.w, h.w, fmaf(w.z, h.z, fmaf(w.y, h.y, fmaf(w.x, h.x, a1n))));
        w = WB[0][j]; a2r = fmaf(w.w, x.w, fmaf(w.z, x.z, fmaf(w.y, x.y, fmaf(w.x, x.x, a2r))));
        w = WB[1][j]; a2z = fmaf(w.w, x.w, fmaf(w.z, x.z, fmaf(w.y, x.y, fmaf(w.x, x.x, a2z))));
        w = WB[2][j]; a2n = fmaf(w.w, x.w, fmaf(w.z, x.z, fmaf(w.y, x.y, fmaf(w.x, x.x, a2n))));
      }
      a1r = wred(a1r); a1z = wred(a1z); a1n = wred(a1n);
      a2r = wred(a2r); a2z = wred(a2z); a2n = wred(a2n);

      float ipr, ipz, ipn, rpr, rpz, rpn;
      if (isL0){ ipr = sc * a2r + bIr[0]; ipz = sc * a2z + bIr[1]; ipn = sc * a2n + bIr[2];
                 rpr = a1r + bRr[0];      rpz = a1z + bRr[1];      rpn = a1n + bRr[2]; }
      else     { ipr = a1r + bIr[0];      ipz = a1z + bIr[1];      ipn = a1n + bIr[2];
                 rpr = a2r + bRr[0];      rpz = a2z + bRr[1];      rpn = a2n + bRr[2]; }

      float r = 1.0f / (1.0f + expf(-(ipr + rpr)));
      float z = 1.0f / (1.0f + expf(-(ipz + rpz)));
      float n = tanhf(ipn + r * rpn);
      hnew = (1.0f - z) * n + z * hprev;

      if (lane == 0){
        if (isb){
          __hip_bfloat16* ob = (__hip_bfloat16*)outv;
          if (isL0 && s == LSEQ - 1) ob[1024 + hidx] = __float2bfloat16(hnew);       // hidden[0]
          if (!isL0 && s == LSEQ)  { ob[hidx] = __float2bfloat16(hnew);              // out
                                     ob[2048 + hidx] = __float2bfloat16(hnew); }     // hidden[1]
        } else {
          float* of = (float*)outv;
          if (isL0 && s == LSEQ - 1) of[1024 + hidx] = hnew;
          if (!isL0 && s == LSEQ)  { of[hidx] = hnew; of[2048 + hidx] = hnew; }
        }
      }
    }
    if (lane == 0) out8[wave] = hnew;   // inactive waves republish hprev

    if (s < LSEQ){
      __syncthreads();   // out8 complete
      if (tid == 0){
        f32x4 d0 = { out8[0], out8[1], out8[2], out8[3] };
        f32x4 d1 = { out8[4], out8[5], out8[6], out8[7] };
        float* dst = hall + wsl * 2048;
        st4_sc(dst + 4 * bid, d0);            // h0 rows 4b..4b+3
        st4_sc(dst + 1024 + 4 * bid, d1);     // h1 rows 4b..4b+3
        asm volatile("s_waitcnt vmcnt(0)" ::: "memory");  // data at LLC
        __hip_atomic_store(&flags[bid], s + 1, __ATOMIC_RELAXED, __HIP_MEMORY_SCOPE_AGENT);
      }
      // prefetch next token's x-row while waiting (normal cached loads)
      if (isL0 && s + 1 < LSEQ){
        int t1 = tok[s + 1];
        sc_next = scale[s + 1];
        xpre0 = load4g(E, (size_t)t1 * 512 + 4 * lane, isb);
        xpre1 = load4g(E, (size_t)t1 * 512 + 4 * lane + 256, isb);
      }
      if (wave == 0){
        const int* fp = flags + 4 * lane;     // 64 lanes x 4 flags = 256
        for (;;){
          i32x4 f = ld4i_sc(fp);
          bool ok = (f.x > s) & (f.y > s) & (f.z > s) & (f.w > s);
          if (__all(ok)) break;
          __builtin_amdgcn_s_sleep(1);
        }
      }
      __syncthreads();
    }
  }
}

extern "C" void kernel_launch(void* const* d_in, const int* in_sizes, int n_in,
                              void* d_out, int out_size, void* d_ws, size_t ws_size,
                              hipStream_t stream) {
  const int*  tokens = (const int*)d_in[0];
  const void* E    = d_in[1];
  const void* Wih0 = d_in[2];
  const void* Whh0 = d_in[3];
  const void* bih0 = d_in[4];
  const void* bhh0 = d_in[5];
  const void* Wih1 = d_in[6];
  const void* Whh1 = d_in[7];
  const void* bih1 = d_in[8];
  const void* bhh1 = d_in[9];
  float* wsf = (float*)d_ws;

  // zero: flags (1KB) + dtype + pad + hall[2][2048] (16KB)
  (void)hipMemsetAsync(d_ws, 0, 18432, stream);
  hipLaunchKernelGGL(detect_dtype, dim3(1), dim3(256), 0, stream,
                     (const unsigned int*)E, ((int*)d_ws) + 256);
  hipLaunchKernelGGL(embed_scale, dim3(1024), dim3(256), 0, stream,
                     tokens, E, ((const int*)d_ws) + 256, wsf + 4608);

  void* args[] = { (void*)&tokens, (void*)&E, (void*)&Wih0, (void*)&Whh0,
                   (void*)&bih0, (void*)&bhh0, (void*)&Wih1, (void*)&Whh1,
                   (void*)&bih1, (void*)&bhh1, (void*)&wsf, (void*)&d_out };
  (void)hipLaunchCooperativeKernel((void*)gru_persistent, dim3(256), dim3(512),
                                   args, 0, stream);
}

// Round 6
// 14798.157 us; speedup vs baseline: 17.3106x; 1.0004x over previous
//
#include <hip/hip_runtime.h>
#include <hip/hip_bf16.h>
#include <stdint.h>

#define LSEQ 4096

typedef float f32x4 __attribute__((ext_vector_type(4)));
typedef int   i32x4 __attribute__((ext_vector_type(4)));

// ---------- helpers ----------
__device__ __forceinline__ float bflo(unsigned int u){ return __uint_as_float(u << 16); }
__device__ __forceinline__ float bfhi(unsigned int u){ return __uint_as_float(u & 0xFFFF0000u); }

__device__ __forceinline__ float wred(float v){
#pragma unroll
  for (int m = 1; m < 64; m <<= 1) v += __shfl_xor(v, m, 64);
  return v;
}

// pin a float4 into VGPRs component-wise
__device__ __forceinline__ void keep4(float4 &v){
  asm volatile("" : "+v"(v.x), "+v"(v.y), "+v"(v.z), "+v"(v.w));
}

// raw LLC-coherent (sc0 sc1) 16B store — fire and forget
__device__ __forceinline__ void st4_sc(float* p, f32x4 v){
  asm volatile("global_store_dwordx4 %0, %1, off sc0 sc1" :: "v"(p), "v"(v) : "memory");
}
// one WG's 3-packet line (48B of a 64B line), single asm block: 3 loads in
// flight + one waitcnt; outputs only valid after the block (airtight vs reorder)
__device__ __forceinline__ void ld_pkt3(const float* p, i32x4 &a, i32x4 &b, i32x4 &c){
  asm volatile("global_load_dwordx4 %0, %3, off sc0 sc1\n\t"
               "global_load_dwordx4 %1, %3, off offset:16 sc0 sc1\n\t"
               "global_load_dwordx4 %2, %3, off offset:32 sc0 sc1\n\t"
               "s_waitcnt vmcnt(0)"
               : "=v"(a), "=v"(b), "=v"(c) : "v"(p) : "memory");
}

// load 4 consecutive elements (bf16 or f32 source) as float4 (normal cached path)
__device__ __forceinline__ float4 load4g(const void* base, size_t off, int isb){
  if (isb){
    uint2 u = *(const uint2*)((const unsigned short*)base + off);
    return make_float4(bflo(u.x), bfhi(u.x), bflo(u.y), bfhi(u.y));
  }
  return *(const float4*)((const float*)base + off);
}
__device__ __forceinline__ float load1g(const void* base, int i, int isb){
  if (isb) return __uint_as_float(((unsigned int)((const unsigned short*)base)[i]) << 16);
  return ((const float*)base)[i];
}

// ---------- dtype detector ----------
__global__ void detect_dtype(const unsigned int* __restrict__ w, int* __restrict__ dflag){
  int tid = threadIdx.x;
  int wild = 0;
  for (int i = tid; i < 4096; i += 256){
    unsigned int lo = w[i] & 0xFFFFu;
    int e = (lo >> 7) & 0xFF;
    if (e < 0x60 || e > 0x9A) wild++;
  }
  __shared__ int cnt;
  if (tid == 0) cnt = 0;
  __syncthreads();
  atomicAdd(&cnt, wild);
  __syncthreads();
  if (tid == 0) *dflag = (cnt * 2 < 4096) ? 1 : 0;
}

// ---------- per-token embedding max-norm scale ----------
__global__ void embed_scale(const int* __restrict__ tok, const void* __restrict__ E,
                            const int* __restrict__ dflag, float* __restrict__ scale){
  int isb = *dflag;
  int t = blockIdx.x * 4 + (threadIdx.x >> 6);
  int lane = threadIdx.x & 63;
  if (t >= LSEQ) return;
  int token = tok[t];
  float ss = 0.f;
#pragma unroll
  for (int j = 0; j < 2; ++j){
    float4 v = load4g(E, (size_t)token * 512 + 4 * lane + 256 * j, isb);
    ss += v.x * v.x + v.y * v.y + v.z * v.z + v.w * v.w;
  }
  ss = wred(ss);
  if (lane == 0){
    float nrm = sqrtf(ss);
    scale[t] = fminf(1.0f, 1.0f / fmaxf(nrm, 1e-7f));
  }
}

// ---------- persistent pipelined 2-layer GRU ----------
// 256 WGs x 512 thr. Waves 0-3: layer0 rows 4b..4b+3; waves 4-7: layer1 rows.
// Exchange: per WG, 3 self-validating 16B packets {3 floats, tag} in a 64B
// line, triple-buffered by s%3 (skew <= 1 superstep => exact-tag poll safe).
// Workspace (floats): [0..12287] hall: 3 slots x 256 WGs x 16 | [12288] dtype
// | [12544..16639] scale.
__global__ __launch_bounds__(512, 2) void gru_persistent(
    const int* __restrict__ tok, const void* __restrict__ E,
    const void* __restrict__ Wih0, const void* __restrict__ Whh0,
    const void* __restrict__ bih0, const void* __restrict__ bhh0,
    const void* __restrict__ Wih1, const void* __restrict__ Whh1,
    const void* __restrict__ bih1, const void* __restrict__ bhh1,
    float* __restrict__ wsf, void* __restrict__ outv)
{
  __shared__ float hb[2048];   // staged h0 (0..1023) | h1 (1024..2047)
  __shared__ float out8[8];    // this WG's 8 new h values
  float* hall = wsf;           // 3 slots x 4096 floats
  const int isb = ((const int*)wsf)[12288];
  const float* scale = wsf + 12544;

  const int tid = threadIdx.x, bid = blockIdx.x;
  const int wave = tid >> 6, lane = tid & 63;
  const bool isL0 = wave < 4;
  const int hidx = bid * 4 + (wave & 3);

  // ---- one-time weight load into registers, pinned ----
  float4 WA[3][4], WB[3][4];
  float bIr[3], bRr[3];
#pragma unroll
  for (int g = 0; g < 3; ++g){
    size_t row = (size_t)(g * 1024 + hidx);
    if (isL0){
#pragma unroll
      for (int j = 0; j < 4; ++j) WA[g][j] = load4g(Whh0, row * 1024 + 4 * lane + 256 * j, isb);
#pragma unroll
      for (int j = 0; j < 2; ++j) WB[g][j] = load4g(Wih0, row * 512 + 4 * lane + 256 * j, isb);
      WB[g][2] = make_float4(0, 0, 0, 0); WB[g][3] = make_float4(0, 0, 0, 0);
      bIr[g] = load1g(bih0, g * 1024 + hidx, isb);
      bRr[g] = load1g(bhh0, g * 1024 + hidx, isb);
    } else {
#pragma unroll
      for (int j = 0; j < 4; ++j) WA[g][j] = load4g(Wih1, row * 1024 + 4 * lane + 256 * j, isb);
#pragma unroll
      for (int j = 0; j < 4; ++j) WB[g][j] = load4g(Whh1, row * 1024 + 4 * lane + 256 * j, isb);
      bIr[g] = load1g(bih1, g * 1024 + hidx, isb);
      bRr[g] = load1g(bhh1, g * 1024 + hidx, isb);
    }
  }
#pragma unroll
  for (int g = 0; g < 3; ++g)
#pragma unroll
    for (int j = 0; j < 4; ++j){ keep4(WA[g][j]); keep4(WB[g][j]); }

  // ---- prologue prefetch: token 0 ----
  float4 xpre0 = make_float4(0,0,0,0), xpre1 = make_float4(0,0,0,0);
  float sc_next = 1.0f;
  if (isL0){
    int t0 = tok[0];
    sc_next = scale[0];
    xpre0 = load4g(E, (size_t)t0 * 512 + 4 * lane, isb);
    xpre1 = load4g(E, (size_t)t0 * 512 + 4 * lane + 256, isb);
  }

  for (int s = 0; s <= LSEQ; ++s){
    // ---- stage: poll WG-tid's packets for tag==s, unpack to LDS ----
    if (tid < 256){
      const float* pk = hall + ((s + 2) % 3) * 4096 + tid * 16;
      i32x4 a, b, c;
      for (;;){
        ld_pkt3(pk, a, b, c);
        if (a.w == s && b.w == s && c.w == s) break;
        __builtin_amdgcn_s_sleep(1);
      }
      hb[4*tid+0] = __int_as_float(a.x); hb[4*tid+1] = __int_as_float(a.y);
      hb[4*tid+2] = __int_as_float(a.z); hb[4*tid+3] = __int_as_float(b.x);
      hb[1024+4*tid+0] = __int_as_float(b.y); hb[1024+4*tid+1] = __int_as_float(b.z);
      hb[1024+4*tid+2] = __int_as_float(c.x); hb[1024+4*tid+3] = __int_as_float(c.y);
    }
    __syncthreads();

    const bool active = isL0 ? (s < LSEQ) : (s >= 1);
    float hprev = isL0 ? hb[hidx] : hb[1024 + hidx];
    float hnew = hprev;
    if (active){
      float4 xr[4];
      float sc = 1.0f;
      if (isL0){
        sc = sc_next;
        xr[0] = xpre0; xr[1] = xpre1;
        xr[2] = make_float4(0,0,0,0); xr[3] = make_float4(0,0,0,0);
      } else {
#pragma unroll
        for (int j = 0; j < 4; ++j) xr[j] = ((const float4*)(hb + 1024))[lane + 64 * j];
      }
      float4 h0r[4];
#pragma unroll
      for (int j = 0; j < 4; ++j) h0r[j] = ((const float4*)hb)[lane + 64 * j];

      float a1r = 0, a1z = 0, a1n = 0, a2r = 0, a2z = 0, a2n = 0;
#pragma unroll
      for (int j = 0; j < 4; ++j){
        float4 h = h0r[j], x = xr[j], w;
        w = WA[0][j]; a1r = fmaf(w.w, h.w, fmaf(w.z, h.z, fmaf(w.y, h.y, fmaf(w.x, h.x, a1r))));
        w = WA[1][j]; a1z = fmaf(w.w, h.w, fmaf(w.z, h.z, fmaf(w.y, h.y, fmaf(w.x, h.x, a1z))));
        w = WA[2][j]; a1n = fmaf(w.w, h.w, fmaf(w.z, h.z, fmaf(w.y, h.y, fmaf(w.x, h.x, a1n))));
        w = WB[0][j]; a2r = fmaf(w.w, x.w, fmaf(w.z, x.z, fmaf(w.y, x.y, fmaf(w.x, x.x, a2r))));
        w = WB[1][j]; a2z = fmaf(w.w, x.w, fmaf(w.z, x.z, fmaf(w.y, x.y, fmaf(w.x, x.x, a2z))));
        w = WB[2][j]; a2n = fmaf(w.w, x.w, fmaf(w.z, x.z, fmaf(w.y, x.y, fmaf(w.x, x.x, a2n))));
      }
      a1r = wred(a1r); a1z = wred(a1z); a1n = wred(a1n);
      a2r = wred(a2r); a2z = wred(a2z); a2n = wred(a2n);

      float ipr, ipz, ipn, rpr, rpz, rpn;
      if (isL0){ ipr = sc * a2r + bIr[0]; ipz = sc * a2z + bIr[1]; ipn = sc * a2n + bIr[2];
                 rpr = a1r + bRr[0];      rpz = a1z + bRr[1];      rpn = a1n + bRr[2]; }
      else     { ipr = a1r + bIr[0];      ipz = a1z + bIr[1];      ipn = a1n + bIr[2];
                 rpr = a2r + bRr[0];      rpz = a2z + bRr[1];      rpn = a2n + bRr[2]; }

      float r = 1.0f / (1.0f + expf(-(ipr + rpr)));
      float z = 1.0f / (1.0f + expf(-(ipz + rpz)));
      float n = tanhf(ipn + r * rpn);
      hnew = (1.0f - z) * n + z * hprev;

      if (lane == 0){
        if (isb){
          __hip_bfloat16* ob = (__hip_bfloat16*)outv;
          if (isL0 && s == LSEQ - 1) ob[1024 + hidx] = __float2bfloat16(hnew);       // hidden[0]
          if (!isL0 && s == LSEQ)  { ob[hidx] = __float2bfloat16(hnew);              // out
                                     ob[2048 + hidx] = __float2bfloat16(hnew); }     // hidden[1]
        } else {
          float* of = (float*)outv;
          if (isL0 && s == LSEQ - 1) of[1024 + hidx] = hnew;
          if (!isL0 && s == LSEQ)  { of[hidx] = hnew; of[2048 + hidx] = hnew; }
        }
      }
    }
    if (lane == 0) out8[wave] = hnew;   // inactive waves republish hprev

    if (s < LSEQ){
      __syncthreads();   // out8 complete
      if (tid == 0){
        float tagf = __int_as_float(s + 1);
        f32x4 P0 = { out8[0], out8[1], out8[2], tagf };
        f32x4 P1 = { out8[3], out8[4], out8[5], tagf };
        f32x4 P2 = { out8[6], out8[7], 0.0f,    tagf };
        float* pk = hall + (s % 3) * 4096 + bid * 16;
        st4_sc(pk,     P0);
        st4_sc(pk + 4, P1);
        st4_sc(pk + 8, P2);   // fire-and-forget: tag travels with data
      }
      // prefetch next token's x-row (normal cached loads; consumed next iter)
      if (isL0 && s + 1 < LSEQ){
        int t1 = tok[s + 1];
        sc_next = scale[s + 1];
        xpre0 = load4g(E, (size_t)t1 * 512 + 4 * lane, isb);
        xpre1 = load4g(E, (size_t)t1 * 512 + 4 * lane + 256, isb);
      }
    }
  }
}

extern "C" void kernel_launch(void* const* d_in, const int* in_sizes, int n_in,
                              void* d_out, int out_size, void* d_ws, size_t ws_size,
                              hipStream_t stream) {
  const int*  tokens = (const int*)d_in[0];
  const void* E    = d_in[1];
  const void* Wih0 = d_in[2];
  const void* Whh0 = d_in[3];
  const void* bih0 = d_in[4];
  const void* bhh0 = d_in[5];
  const void* Wih1 = d_in[6];
  const void* Whh1 = d_in[7];
  const void* bih1 = d_in[8];
  const void* bhh1 = d_in[9];
  float* wsf = (float*)d_ws;

  // zero the 3-slot packet arena (tags must start at 0)
  (void)hipMemsetAsync(d_ws, 0, 49152, stream);
  hipLaunchKernelGGL(detect_dtype, dim3(1), dim3(256), 0, stream,
                     (const unsigned int*)E, ((int*)d_ws) + 12288);
  hipLaunchKernelGGL(embed_scale, dim3(1024), dim3(256), 0, stream,
                     tokens, E, ((const int*)d_ws) + 12288, wsf + 12544);

  void* args[] = { (void*)&tokens, (void*)&E, (void*)&Wih0, (void*)&Whh0,
                   (void*)&bih0, (void*)&bhh0, (void*)&Wih1, (void*)&Whh1,
                   (void*)&bih1, (void*)&bhh1, (void*)&wsf, (void*)&d_out };
  (void)hipLaunchCooperativeKernel((void*)gru_persistent, dim3(256), dim3(512),
                                   args, 0, stream);
}